// Round 4
// baseline (134.843 us; speedup 1.0000x reference)
//
#include <hip/hip_runtime.h>

// ReservoirEmbedding: out[tok,:] = sum_r w_eff[reservoir_lookup[base_indices[tok], r], :]
// w_eff row 0 zeroed. base [16,2048] i32, lookup [50257,8] i32, weight [50257,128] f32.
//
// R3: vocab-slice phasing. 8 phases; phase j gathers only rows in
// [j*6283, (j+1)*6283) (3.2 MB — fits per-XCD 4MB L2). All blocks co-resident
// and phase-aligned => all 8 XCD L2s cache the current slice => gathers become
// L2 hits instead of L3 hits. Discriminates MSHR-latency cap (predict ~15us)
// vs L3-bandwidth cap (predict ~35us, worse).

#define VOCAB 50257
#define FEATURES 128
#define RESERVOIR 8
#define NTOK (16 * 2048)
#define TPG 4           // tokens per 32-lane group
#define NSLICE 8
#define SLICEW 6283     // ceil(VOCAB/8); 8*6283 = 50264 >= 50257

typedef float float4v __attribute__((ext_vector_type(4)));

__global__ __launch_bounds__(256) void reservoir_embed_kernel(
    const int* __restrict__ base_indices,      // [NTOK]
    const int* __restrict__ reservoir_lookup,  // [VOCAB][RESERVOIR]
    const float* __restrict__ weight,          // [VOCAB][FEATURES]
    float* __restrict__ out)                   // [NTOK][FEATURES]
{
    const int gid  = blockIdx.x * blockDim.x + threadIdx.x;
    const int grp  = gid >> 5;        // 32-lane group
    const int lane = gid & 31;        // lane owns features [4*lane, 4*lane+4)
    const int t0   = grp * TPG;

    // 4 base indices in one 16B load.
    const int4 b4 = *reinterpret_cast<const int4*>(base_indices + t0);
    const int bases[TPG] = {b4.x, b4.y, b4.z, b4.w};

    // 8 reservoir indices per token (2x int4 each; rows are 32B-aligned).
    int idx[TPG][RESERVOIR];
#pragma unroll
    for (int t = 0; t < TPG; ++t) {
        const int4* rlp = reinterpret_cast<const int4*>(
            reservoir_lookup + bases[t] * RESERVOIR);
        const int4 i0 = rlp[0];
        const int4 i1 = rlp[1];
        idx[t][0] = i0.x; idx[t][1] = i0.y; idx[t][2] = i0.z; idx[t][3] = i0.w;
        idx[t][4] = i1.x; idx[t][5] = i1.y; idx[t][6] = i1.z; idx[t][7] = i1.w;
    }

    float4v acc[TPG];
#pragma unroll
    for (int t = 0; t < TPG; ++t) acc[t] = (float4v){0.f, 0.f, 0.f, 0.f};

    // Phase loop over vocab slices: only gather rows in the current slice so
    // the whole chip's working set at any instant is one 3.2MB slice.
    for (int j = 0; j < NSLICE; ++j) {
        const unsigned lo = (unsigned)(j * SLICEW);
#pragma unroll
        for (int t = 0; t < TPG; ++t) {
#pragma unroll
            for (int r = 0; r < RESERVOIR; ++r) {
                const unsigned d = (unsigned)idx[t][r] - lo;
                if (d < SLICEW) {
                    const float4v row = *reinterpret_cast<const float4v*>(
                        weight + (((unsigned)idx[t][r]) << 7) + (lane << 2));
                    const float m = (idx[t][r] != 0) ? 1.0f : 0.0f;  // frozen row 0
                    acc[t] += m * row;
                }
            }
        }
        __syncthreads();   // keep the block's 16 waves phase-aligned
    }

#pragma unroll
    for (int t = 0; t < TPG; ++t) {
        float4v* op = reinterpret_cast<float4v*>(
            out + (unsigned)(t0 + t) * FEATURES + (lane << 2));
        __builtin_nontemporal_store(acc[t], op);  // don't pollute L2 with out
    }
}

extern "C" void kernel_launch(void* const* d_in, const int* in_sizes, int n_in,
                              void* d_out, int out_size, void* d_ws, size_t ws_size,
                              hipStream_t stream) {
    (void)in_sizes; (void)n_in; (void)out_size; (void)d_ws; (void)ws_size;
    const int*   base_indices     = (const int*)d_in[0];
    const int*   reservoir_lookup = (const int*)d_in[1];
    const float* weight           = (const float*)d_in[2];
    float*       out              = (float*)d_out;

    const int threads = 256;                       // 8 groups of 32 lanes
    const int groups  = NTOK / TPG;                // 8192 groups
    const int blocks  = groups * 32 / threads;     // 1024 blocks = 4/CU, co-resident
    reservoir_embed_kernel<<<blocks, threads, 0, stream>>>(
        base_indices, reservoir_lookup, weight, out);
}

// Round 5
// 24.149 us; speedup vs baseline: 5.5838x; 5.5838x over previous
//
#include <hip/hip_runtime.h>

// ReservoirEmbedding: out[tok,:] = sum_r w_eff[reservoir_lookup[base_indices[tok], r], :]
// w_eff row 0 zeroed. base [16,2048] i32, lookup [50257,8] i32, weight [50257,128] f32.
//
// R4: slice-SORTED gather issue (not filtered). Each lane owns one (t,r) pair
// (32 per 32-lane group); indices bucket-ranked by vocab slice (idx>>12, 2MB
// slices) via ballots, reordered through LDS, then ALL 32 row-gathers issued
// unconditionally in sorted order. Full MLP + chip-wide slice-coherent
// in-flight window -> L2 hits -> lower avg latency under the per-CU
// outstanding-line cap. VGPR capped (256,4) so all 1024 blocks co-resident.

#define VOCAB 50257
#define FEATURES 128
#define RESERVOIR 8
#define NTOK (16 * 2048)
#define TPG 4            // tokens per 32-lane group (32 pairs = 1/lane)
#define SLICE_SHIFT 12   // 4096-row slices = 2MB

typedef float float4v __attribute__((ext_vector_type(4)));

__global__ __launch_bounds__(256, 4) void reservoir_embed_kernel(
    const int* __restrict__ base_indices,      // [NTOK]
    const int* __restrict__ reservoir_lookup,  // [VOCAB][RESERVOIR]
    const float* __restrict__ weight,          // [VOCAB][FEATURES]
    float* __restrict__ out)                   // [NTOK][FEATURES]
{
    const int tid  = threadIdx.x;
    const int gid  = blockIdx.x * 256 + tid;
    const int grp  = gid >> 5;          // 32-lane group
    const int lane = gid & 31;          // lane within group
    const int half = (tid >> 5) & 1;    // which half of the wave64
    const int t0   = grp * TPG;

    // Each lane owns pair (t = lane>>3, r = lane&7).
    const int t = lane >> 3;
    const int r = lane & 7;
    const int base  = base_indices[t0 + t];                  // 8 lanes/addr -> broadcast
    const int myidx = reservoir_lookup[base * RESERVOIR + r]; // 4x 32B segments/group

    // Bucket-rank within the 32-lane group by slice = myidx>>12 (buckets 0..12).
    const int s = myidx >> SLICE_SHIFT;
    const unsigned below = (1u << lane) - 1u;
    int rank = 0;
    for (int k = 0; k < 16; ++k) {
        unsigned long long b = __ballot(s == k);
        unsigned m = (unsigned)(b >> (half * 32));
        if (k < s)       rank += __popc(m);
        else if (k == s) rank += __popc(m & below);
    }

    // key packs (idx, t); sort-permute through LDS (group-private 32-slot
    // segment, same wave for both halves -> no block barrier needed).
    const int key = (myidx << 2) | t;
    __shared__ int smem[256];
    smem[(tid & ~31) + rank] = key;
    const int skey = smem[tid];   // sorted key at position `lane`

    float4v acc[TPG];
#pragma unroll
    for (int i = 0; i < TPG; ++i) acc[i] = (float4v){0.f, 0.f, 0.f, 0.f};

    // Two batches of 16 rows (keeps VGPR <= 128 for 4 waves/SIMD).
#pragma unroll
    for (int b = 0; b < 2; ++b) {
        int keys[16];
        float4v rows[16];
#pragma unroll
        for (int i = 0; i < 16; ++i) {
            keys[i] = __shfl(skey, b * 16 + i, 32);
            const float* p = weight + (((unsigned)keys[i] >> 2) << 7) + (lane << 2);
            rows[i] = *reinterpret_cast<const float4v*>(p);
        }
#pragma unroll
        for (int i = 0; i < 16; ++i) {
            const int kk = keys[i];
            const int tt = kk & 3;
            const float m = ((kk >> 2) != 0) ? 1.0f : 0.0f;  // frozen row 0
            acc[0] += ((tt == 0) ? m : 0.0f) * rows[i];
            acc[1] += ((tt == 1) ? m : 0.0f) * rows[i];
            acc[2] += ((tt == 2) ? m : 0.0f) * rows[i];
            acc[3] += ((tt == 3) ? m : 0.0f) * rows[i];
        }
    }

#pragma unroll
    for (int i = 0; i < TPG; ++i) {
        float4v* op = reinterpret_cast<float4v*>(
            out + (unsigned)(t0 + i) * FEATURES + (lane << 2));
        __builtin_nontemporal_store(acc[i], op);
    }
}

extern "C" void kernel_launch(void* const* d_in, const int* in_sizes, int n_in,
                              void* d_out, int out_size, void* d_ws, size_t ws_size,
                              hipStream_t stream) {
    (void)in_sizes; (void)n_in; (void)out_size; (void)d_ws; (void)ws_size;
    const int*   base_indices     = (const int*)d_in[0];
    const int*   reservoir_lookup = (const int*)d_in[1];
    const float* weight           = (const float*)d_in[2];
    float*       out              = (float*)d_out;

    const int threads = 256;                    // 8 groups of 32 lanes
    const int groups  = NTOK / TPG;             // 8192 groups
    const int blocks  = groups * 32 / threads;  // 1024 blocks = 4/CU co-resident
    reservoir_embed_kernel<<<blocks, threads, 0, stream>>>(
        base_indices, reservoir_lookup, weight, out);
}